// Round 11
// baseline (187.340 us; speedup 1.0000x reference)
//
#include <hip/hip_runtime.h>
#include <hip/hip_bf16.h>
#include <math.h>

// Problem constants
#define B_  8
#define T_  2048
#define C_  768
#define HS_ 256

// Split-K flash: q-block = 128 rows (32 q per wave, 2 q-groups), k-tile = 32
// keys, chunk = 8 k-tiles (256 keys). q-block qb (0..15) has 4qb+4 k-tiles;
// chunks(qb) = (qb>>1)+1; per-batch chunk total = 72; blocks = 8*72 = 576.
// R18: R14 compute body (K/V fragment reads amortized over 2 q-groups ->
// LDS-pipe cycles per unit work HALVED; R17 analysis: LDS pipe ~2100
// cyc/64-row tile is the floor) on R12's proven sync skeleton (SINGLE-
// buffered K/V, 2 barriers/tile, block-shared staging, 40 KB LDS).
#define CHUNKS_PER_BATCH 72
#define NSLOT (CHUNKS_PER_BATCH * B_)   // 576

typedef float  f32x4  __attribute__((ext_vector_type(4)));
typedef __bf16 bf16x8 __attribute__((ext_vector_type(8)));
typedef __bf16 bf16x4 __attribute__((ext_vector_type(4)));
typedef __bf16 bf16x2 __attribute__((ext_vector_type(2)));

#define MFMA16(a, b, c) __builtin_amdgcn_mfma_f32_16x16x32_bf16((a), (b), (c), 0, 0, 0)

// global->LDS async copy, 16B per lane (dest = wave-uniform base + lane*16)
#define GLOAD_LDS16(gp, lp)                                                     \
    __builtin_amdgcn_global_load_lds(                                           \
        (const __attribute__((address_space(1))) void*)(gp),                    \
        (__attribute__((address_space(3))) void*)(lp), 16, 0, 0)

// cumulative chunk count before 128-row q-block qb: g=qb>>1 -> g(g+1)+(qb&1)(g+1)
__device__ __forceinline__ int chunk_cum128(int qb) {
    int g = qb >> 1;
    return g * (g + 1) + (qb & 1) * (g + 1);
}

// ---------------------------------------------------------------------------
// Kernel 0: prep = x cast (blocks 0..6143) + weight transpose (6144..6431).
// ---------------------------------------------------------------------------
__global__ __launch_bounds__(256) void prep_kernel(const float* __restrict__ x,
                                                   const float* __restrict__ Wq,
                                                   const float* __restrict__ Wk,
                                                   const float* __restrict__ Wv,
                                                   __bf16* __restrict__ xb,
                                                   __bf16* __restrict__ wt_all,
                                                   float qscale) {
    const int bid = blockIdx.x;
    if (bid < 6144) {
        size_t i = ((size_t)bid * 256 + threadIdx.x) * 8;
        f32x4 a = *(const f32x4*)(x + i);
        f32x4 b = *(const f32x4*)(x + i + 4);
        bf16x8 o;
        o[0] = (__bf16)a[0]; o[1] = (__bf16)a[1]; o[2] = (__bf16)a[2]; o[3] = (__bf16)a[3];
        o[4] = (__bf16)b[0]; o[5] = (__bf16)b[1]; o[6] = (__bf16)b[2]; o[7] = (__bf16)b[3];
        *(bf16x8*)(xb + i) = o;
    } else {
        int idx = (bid - 6144) * 256 + threadIdx.x;   // [0, 73728)
        int n   = idx & 255;
        int t   = idx >> 8;          // [0, 288) = mat*96 + k8
        int mat = t / 96;
        int k8  = t - mat * 96;
        const float* W = (mat == 0) ? Wq : ((mat == 1) ? Wk : Wv);
        float scale = (mat == 0) ? qscale : 1.0f;
        bf16x8 o;
#pragma unroll
        for (int j = 0; j < 8; j++)
            o[j] = (__bf16)(W[(k8 * 8 + j) * HS_ + n] * scale);
        *(bf16x8*)&wt_all[((size_t)mat * HS_ + n) * C_ + k8 * 8] = o;
    }
}

// ---------------------------------------------------------------------------
// Kernel 2: fused QKV GEMM. BK=32, double-buffered LDS, one barrier/iter.
//   Q/K tiles: swapped operands (C rows carry d) -> coalesced bf16x4 stores.
// Fragment layouts (element index, all *8 = 8 bf16 per lane slot):
//   Q: ((((b*32+qt)*4 + w16)*8 + ks )*64 + lane)   lane&15 = q, quad = (d>>3)&3, j = d&7
//   K: ((((b*32+kt)*8 + ks )*4 + ns )*64 + lane)   lane&15 = s, quad = (d>>3)&3, j = d&7
//   V: ((((b*32+kt)*2 + ks2)*16 + ntv)*64 + lane)  lane&15 = d, quad = (s>>3)&3, j = s&7
// ---------------------------------------------------------------------------
__global__ __launch_bounds__(256) void proj_kernel(const __bf16* __restrict__ xb,
                                                   const __bf16* __restrict__ wt,
                                                   __bf16* __restrict__ qf_,
                                                   __bf16* __restrict__ kf_,
                                                   __bf16* __restrict__ vf_) {
    __shared__ alignas(16) __bf16 ldsA[2][128 * 32];   // 2 x 8 KB
    __shared__ alignas(16) __bf16 ldsB[2][128 * 32];   // 2 x 8 KB

    const int tid  = threadIdx.x;
    const int w    = tid >> 6;
    const int lane = tid & 63;
    const int cm   = lane & 15;
    const int quad = lane >> 4;
    const int wm   = w & 1;
    const int wn   = w >> 1;
    const int m0   = blockIdx.x * 128;
    const int n0   = blockIdx.y * 128;
    const int mat  = n0 >> 8;                 // 0=Q 1=K 2=V

    f32x4 acc[4][4];
#pragma unroll
    for (int i = 0; i < 4; i++)
#pragma unroll
        for (int j = 0; j < 4; j++) acc[i][j] = (f32x4){0.f, 0.f, 0.f, 0.f};

    // prologue: stage k-iter 0 into buffer 0
#pragma unroll
    for (int h = 0; h < 2; h++) {
        int c = tid + h * 256;   // 512 chunks: row = c>>2, col granule = (c&3)*8
        GLOAD_LDS16(xb + (size_t)(m0 + (c >> 2)) * C_ + (c & 3) * 8, &ldsA[0][c * 8]);
        GLOAD_LDS16(wt + (size_t)(n0 + (c >> 2)) * C_ + (c & 3) * 8, &ldsB[0][c * 8]);
    }

    for (int kt = 0; kt < 24; kt++) {
        const int cur = kt & 1;
        __syncthreads();   // drains vmcnt -> buf[cur] staged; prev reads done

        if (kt < 23) {
            const int k0 = (kt + 1) * 32;
#pragma unroll
            for (int h = 0; h < 2; h++) {
                int c = tid + h * 256;
                GLOAD_LDS16(xb + (size_t)(m0 + (c >> 2)) * C_ + k0 + (c & 3) * 8,
                            &ldsA[cur ^ 1][c * 8]);
                GLOAD_LDS16(wt + (size_t)(n0 + (c >> 2)) * C_ + k0 + (c & 3) * 8,
                            &ldsB[cur ^ 1][c * 8]);
            }
        }

        bf16x8 af[4], bfr[4];
#pragma unroll
        for (int mt = 0; mt < 4; mt++)
            af[mt] = *(const bf16x8*)&ldsA[cur][(wm * 64 + mt * 16 + cm) * 32 + quad * 8];
#pragma unroll
        for (int nt = 0; nt < 4; nt++)
            bfr[nt] = *(const bf16x8*)&ldsB[cur][(wn * 64 + nt * 16 + cm) * 32 + quad * 8];
        if (mat < 2) {
#pragma unroll
            for (int dt = 0; dt < 4; dt++)
#pragma unroll
                for (int qt2 = 0; qt2 < 4; qt2++)
                    acc[dt][qt2] = MFMA16(bfr[dt], af[qt2], acc[dt][qt2]);
        } else {
#pragma unroll
            for (int mt = 0; mt < 4; mt++)
#pragma unroll
                for (int nt = 0; nt < 4; nt++)
                    acc[mt][nt] = MFMA16(af[mt], bfr[nt], acc[mt][nt]);
        }
    }

    const int dBase = (n0 & 255) + wn * 64;
    const int b     = m0 >> 11;
    if (mat < 2) {
        const int rt2 = ((m0 & 2047) >> 6) + wm;   // 64-row tile within batch
        __bf16* dst = (mat == 0) ? qf_ : kf_;
#pragma unroll
        for (int dt = 0; dt < 4; dt++)
#pragma unroll
            for (int qt2 = 0; qt2 < 4; qt2++) {
                int d0    = dBase + dt * 16 + quad * 4;   // d of reg i = d0 + i
                int ksq   = d0 >> 5;
                int quadp = (d0 >> 3) & 3;
                int j0    = d0 & 7;
                size_t addr;
                if (mat == 0)
                    addr = ((((size_t)(b * 32 + rt2) * 4 + qt2) * 8 + ksq) * 64
                            + quadp * 16 + cm) * 8 + j0;
                else
                    addr = ((((size_t)(b * 32 + rt2) * 8 + ksq) * 4 + qt2) * 64
                            + quadp * 16 + cm) * 8 + j0;
                bf16x4 v4;
                v4[0] = (__bf16)acc[dt][qt2][0]; v4[1] = (__bf16)acc[dt][qt2][1];
                v4[2] = (__bf16)acc[dt][qt2][2]; v4[3] = (__bf16)acc[dt][qt2][3];
                *(bf16x4*)(dst + addr) = v4;
            }
    } else {
        const int rt = ((m0 & 2047) + wm * 64) >> 6;
#pragma unroll
        for (int mt = 0; mt < 4; mt++) {
            int ks2   = (mt >> 1) & 1;
            int quadF = (mt & 1) * 2 + (quad >> 1);
            int jb    = (quad & 1) * 4;
#pragma unroll
            for (int nt = 0; nt < 4; nt++) {
                int ntv = (dBase >> 4) + nt;
                size_t idx = ((((size_t)(b * 32 + rt) * 2 + ks2) * 16 + ntv) * 64
                              + quadF * 16 + cm) * 8 + jb;
                bf16x4 v4;
                v4[0] = (__bf16)acc[mt][nt][0]; v4[1] = (__bf16)acc[mt][nt][1];
                v4[2] = (__bf16)acc[mt][nt][2]; v4[3] = (__bf16)acc[mt][nt][3];
                *(bf16x4*)(vf_ + idx) = v4;
            }
        }
    }
}

// ---------------------------------------------------------------------------
// Kernel 3a: split-K causal flash partial — R18 (resubmit): R14's verified
//   compute body (32 q per wave = 2 q-groups; each kfr/vfr LDS read feeds
//   TWO MFMAs -> LDS-pipe cycles per unit work halved) on R12's proven sync
//   skeleton (SINGLE-buffered K/V 16+16 KB + 8 KB P = 40 KB, 2 barriers/
//   tile, block-shared staging). 128-row q-blocks, 8-tile chunks, 576
//   blocks. launch_bounds(256,2): ~240 unified regs (accO->AGPR), no spill.
// ---------------------------------------------------------------------------
__global__ __launch_bounds__(256, 2) void flash_part(const __bf16* __restrict__ qf_,
                                                     const __bf16* __restrict__ kf_,
                                                     const __bf16* __restrict__ vf_,
                                                     __bf16* __restrict__ Opart,
                                                     float* __restrict__ mpart,
                                                     float* __restrict__ lpart) {
    __shared__ alignas(16) __bf16 ldsK[8 * 2 * 64 * 8];   // 16 KB
    __shared__ alignas(16) __bf16 ldsV[16 * 64 * 8];      // 16 KB
    __shared__ alignas(16) __bf16 ldsP[4][2][512];        // per-wave P, 2 qg (8 KB)

    const int tid  = threadIdx.x;
    const int w    = tid >> 6;       // 0..3
    const int lane = tid & 63;
    const int cm   = lane & 15;      // = q column (within 16-row group)
    const int quad = lane >> 4;

    const int pid  = blockIdx.x;                // [0, 576)
    const int b    = pid & 7;                   // batch -> XCD spread
    const int r    = (CHUNKS_PER_BATCH - 1) - (pid >> 3);   // heavy chunks first
    int qb = 0, ci = 0;
    {
        int rr = r;
        for (int j = 0; j < 16; j++) {
            int c = (j >> 1) + 1;               // chunks for 128-row q-block j
            if (rr < c) { qb = j; ci = rr; break; }
            rr -= c;
        }
    }
    const int lpid = b * CHUNKS_PER_BATCH + r;  // output slot
    const int kt_begin = ci * 8;                        // 32-key tiles
    const int kt_end   = min(kt_begin + 8, 4 * qb + 4);

    // Q fragments: wave w owns rows [qb*128 + w*32, +32) = 2 x 16-row groups.
    bf16x8 qf2[2][8];
#pragma unroll
    for (int qg = 0; qg < 2; qg++) {
        int g16 = qb * 8 + w * 2 + qg;
        const __bf16* qp = qf_ + (((size_t)(b * 32 + (g16 >> 2)) * 4 + (g16 & 3)) * 8) * 512
                           + lane * 8;
#pragma unroll
        for (int ks = 0; ks < 8; ks++) qf2[qg][ks] = *(const bf16x8*)(qp + ks * 512);
    }

    f32x4 accO[2][16];   // accO[qg][nt][i]: d = nt*16 + quad*4 + i, q = qg*16+cm
#pragma unroll
    for (int qg = 0; qg < 2; qg++)
#pragma unroll
        for (int i = 0; i < 16; i++) accO[qg][i] = (f32x4){0.f, 0.f, 0.f, 0.f};
    float mi[2] = {0.f, 0.f}, li[2] = {0.f, 0.f};   // fixed anchor after first tile

    const int wrow = qb * 128 + w * 32;             // wave's min q row

    for (int kt = kt_begin; kt < kt_end; kt++) {
        __syncthreads();   // (A) prior tile's LDS fully consumed

        // ---- stage K (16 KB) + V (16 KB) tile, async, block-shared ----
        {
            const int kt64 = kt >> 1, kh = kt & 1;
            const __bf16* kgb = kf_ + (((size_t)(b * 32 + kt64) * 8) * 4 + kh * 2) * 512;
#pragma unroll
            for (int h = 0; h < 4; h++) {
                int g = h * 256 + tid;           // 16B slot id, 0..1023
                int ks = g >> 7, sub = g & 127;  // sub = ns2*64 + lane'
                GLOAD_LDS16(kgb + (size_t)ks * 4 * 512 + sub * 8,
                            ldsK + (h * 256 + w * 64) * 8);
            }
            const __bf16* vgb = vf_ + ((size_t)(b * 64 + kt) * 16) * 512;
#pragma unroll
            for (int h = 0; h < 4; h++) {
                int g = h * 256 + tid;           // ntv = g>>6, lane' = g&63
                GLOAD_LDS16(vgb + (size_t)g * 8,
                            ldsV + (h * 256 + w * 64) * 8);
            }
        }
        __syncthreads();   // (B) vmcnt drained -> K/V visible

        // ---- St = K Q^T  (32 s x 32 q per wave); kfr shared across qg ----
        f32x4 s[2][2];   // [ns][qg]
#pragma unroll
        for (int ns = 0; ns < 2; ns++)
#pragma unroll
            for (int qg = 0; qg < 2; qg++) s[ns][qg] = (f32x4){0.f, 0.f, 0.f, 0.f};
        __builtin_amdgcn_s_setprio(1);
#pragma unroll
        for (int ns = 0; ns < 2; ns++)
#pragma unroll
            for (int ks = 0; ks < 8; ks++) {
                bf16x8 kfr = *(const bf16x8*)&ldsK[(ks * 2 + ns) * 512 + lane * 8];
                s[ns][0] = MFMA16(kfr, qf2[0][ks], s[ns][0]);
                s[ns][1] = MFMA16(kfr, qf2[1][ks], s[ns][1]);
            }
        __builtin_amdgcn_s_setprio(0);
        // ---- causal mask (key = kt*32 + ns*16 + quad*4 + i; q = wrow+qg*16+cm) ----
        if (kt * 32 + 31 > wrow) {
#pragma unroll
            for (int qg = 0; qg < 2; qg++) {
                int qglob = wrow + qg * 16 + cm;
#pragma unroll
                for (int ns = 0; ns < 2; ns++)
#pragma unroll
                    for (int i = 0; i < 4; i++)
                        if (kt * 32 + ns * 16 + quad * 4 + i > qglob)
                            s[ns][qg][i] = -__builtin_inff();
            }
        }
        // ---- fixed-anchor softmax: establish m once (first tile) ----
        if (kt == kt_begin) {
#pragma unroll
            for (int qg = 0; qg < 2; qg++) {
                float pm = -__builtin_inff();
#pragma unroll
                for (int ns = 0; ns < 2; ns++)
#pragma unroll
                    for (int i = 0; i < 4; i++) pm = fmaxf(pm, s[ns][qg][i]);
                pm = fmaxf(pm, __shfl_xor(pm, 16));
                pm = fmaxf(pm, __shfl_xor(pm, 32));
                mi[qg] = pm;
            }
        }
        float p[2][2][4];   // [qg][ns][i]
        float rs[2] = {0.f, 0.f};
#pragma unroll
        for (int qg = 0; qg < 2; qg++)
#pragma unroll
            for (int ns = 0; ns < 2; ns++)
#pragma unroll
                for (int i = 0; i < 4; i++) {
                    p[qg][ns][i] = exp2f(s[ns][qg][i] - mi[qg]);
                    rs[qg] += p[qg][ns][i];
                }
#pragma unroll
        for (int qg = 0; qg < 2; qg++) {
            rs[qg] += __shfl_xor(rs[qg], 16);
            rs[qg] += __shfl_xor(rs[qg], 32);
            li[qg] += rs[qg];
        }

        // ---- P -> private per-wave LDS in PV B-operand layout (per qg) ----
#pragma unroll
        for (int qg = 0; qg < 2; qg++)
#pragma unroll
            for (int ns = 0; ns < 2; ns++)
#pragma unroll
                for (int i2 = 0; i2 < 2; i2++) {
                    bf16x2 d2;
                    d2[0] = (__bf16)p[qg][ns][2 * i2];
                    d2[1] = (__bf16)p[qg][ns][2 * i2 + 1];
                    int off = ((ns * 2 + (quad >> 1)) * 16 + cm) * 8
                              + (quad & 1) * 4 + i2 * 2;
                    *(bf16x2*)&ldsP[w][qg][off] = d2;
                }
        // ---- O += V^T-frag x P-frag; vfr shared across qg ----
        bf16x8 pf0 = *(const bf16x8*)&ldsP[w][0][(quad * 16 + cm) * 8];
        bf16x8 pf1 = *(const bf16x8*)&ldsP[w][1][(quad * 16 + cm) * 8];
        __builtin_amdgcn_s_setprio(1);
#pragma unroll
        for (int nt = 0; nt < 16; nt++) {
            bf16x8 vfr = *(const bf16x8*)&ldsV[(nt * 64 + lane) * 8];
            accO[0][nt] = MFMA16(vfr, pf0, accO[0][nt]);
            accO[1][nt] = MFMA16(vfr, pf1, accO[1][nt]);
        }
        __builtin_amdgcn_s_setprio(0);
    }

    // ---- epilogue: coalesced bf16x4 stores + fp32 (m, l) ----
#pragma unroll
    for (int qg = 0; qg < 2; qg++) {
        __bf16* op = Opart + ((size_t)lpid * 128 + w * 32 + qg * 16 + cm) * HS_;
#pragma unroll
        for (int nt = 0; nt < 16; nt++) {
            bf16x4 v4;
            v4[0] = (__bf16)accO[qg][nt][0]; v4[1] = (__bf16)accO[qg][nt][1];
            v4[2] = (__bf16)accO[qg][nt][2]; v4[3] = (__bf16)accO[qg][nt][3];
            *(bf16x4*)(op + nt * 16 + quad * 4) = v4;
        }
        if (quad == 0) {
            mpart[lpid * 128 + w * 32 + qg * 16 + cm] = mi[qg];
            lpart[lpid * 128 + w * 32 + qg * 16 + cm] = li[qg];
        }
    }
}

// ---------------------------------------------------------------------------
// Kernel 3b: combine partials.  Grid (128, 8): block = (b, qb) x 16 rows.
// ---------------------------------------------------------------------------
__global__ __launch_bounds__(256) void flash_combine(const __bf16* __restrict__ Opart,
                                                     const float* __restrict__ mpart,
                                                     const float* __restrict__ lpart,
                                                     float* __restrict__ out) {
    const int b    = blockIdx.x >> 4;
    const int qb   = blockIdx.x & 15;
    const int nc   = (qb >> 1) + 1;
    const int pid0 = b * CHUNKS_PER_BATCH + chunk_cum128(qb);

    const int tid  = threadIdx.x;
    const int col  = (tid & 63) * 4;
    const int r0   = blockIdx.y * 16 + (tid >> 6) * 4;

    f32x4 ms = (f32x4){-__builtin_inff(), -__builtin_inff(),
                       -__builtin_inff(), -__builtin_inff()};
    for (int c = 0; c < nc; c++) {
        f32x4 m4 = *(const f32x4*)(mpart + (pid0 + c) * 128 + r0);
#pragma unroll
        for (int i = 0; i < 4; i++) ms[i] = fmaxf(ms[i], m4[i]);
    }
    f32x4 acc[4];
#pragma unroll
    for (int i = 0; i < 4; i++) acc[i] = (f32x4){0.f, 0.f, 0.f, 0.f};
    f32x4 lt = (f32x4){0.f, 0.f, 0.f, 0.f};
    for (int c = 0; c < nc; c++) {
        f32x4 m4 = *(const f32x4*)(mpart + (pid0 + c) * 128 + r0);
        f32x4 l4 = *(const f32x4*)(lpart + (pid0 + c) * 128 + r0);
#pragma unroll
        for (int i = 0; i < 4; i++) {
            float sc = exp2f(m4[i] - ms[i]);
            lt[i] += l4[i] * sc;
            bf16x4 o = *(const bf16x4*)(Opart
                        + ((size_t)(pid0 + c) * 128 + r0 + i) * HS_ + col);
            acc[i][0] += (float)o[0] * sc; acc[i][1] += (float)o[1] * sc;
            acc[i][2] += (float)o[2] * sc; acc[i][3] += (float)o[3] * sc;
        }
    }
#pragma unroll
    for (int i = 0; i < 4; i++) {
        float inv = 1.0f / lt[i];
        f32x4 res = (f32x4){acc[i][0] * inv, acc[i][1] * inv,
                            acc[i][2] * inv, acc[i][3] * inv};
        *(f32x4*)(out + ((size_t)(b * T_ + qb * 128 + r0 + i)) * HS_ + col) = res;
    }
}

// ---------------------------------------------------------------------------
extern "C" void kernel_launch(void* const* d_in, const int* in_sizes, int n_in,
                              void* d_out, int out_size, void* d_ws, size_t ws_size,
                              hipStream_t stream) {
    const float* x  = (const float*)d_in[0];
    const float* Wq = (const float*)d_in[1];
    const float* Wk = (const float*)d_in[2];
    const float* Wv = (const float*)d_in[3];
    float* out = (float*)d_out;

    char* ws = (char*)d_ws;
    size_t off = 0;
    __bf16* wt_all = (__bf16*)(ws + off); off += 1179648;
    __bf16* qfrag  = (__bf16*)(ws + off); off += 8388608;
    __bf16* kfrag  = (__bf16*)(ws + off); off += 8388608;
    __bf16* vfrag  = (__bf16*)(ws + off); off += 8388608;
    __bf16* xb     = (__bf16*)(ws + off);              // union with Opart
    __bf16* Opart  = (__bf16*)(ws + off); off += (size_t)NSLOT * 128 * HS_ * 2;
    float*  mpart  = (float*)(ws + off);  off += (size_t)NSLOT * 128 * 4;
    float*  lpart  = (float*)(ws + off);

    float qscale = 1.4426950408889634f / sqrtf((float)C_);

    prep_kernel<<<dim3(6432), 256, 0, stream>>>(x, Wq, Wk, Wv, xb, wt_all, qscale);
    proj_kernel<<<dim3(128, 6), 256, 0, stream>>>(xb, wt_all, qfrag, kfrag, vfrag);
    flash_part<<<dim3(NSLOT), 256, 0, stream>>>(qfrag, kfrag, vfrag, Opart, mpart, lpart);
    flash_combine<<<dim3(128, 8), 256, 0, stream>>>(Opart, mpart, lpart, out);
}

// Round 12
// 174.559 us; speedup vs baseline: 1.0732x; 1.0732x over previous
//
#include <hip/hip_runtime.h>
#include <hip/hip_bf16.h>
#include <math.h>

// Problem constants
#define B_  8
#define T_  2048
#define C_  768
#define HS_ 256

// Split-K flash: q-block = 64 rows, k-tile = 32 keys, chunk = 16 k-tiles
// (512 keys). q-block qb (0..31) has 2qb+2 k-tiles; chunks(qb) = (qb>>3)+1;
// per-batch chunk total = 80; blocks = 8 * 80 = 640.   (= round-0 champion)
#define CHUNKS_PER_BATCH 80
#define NSLOT (CHUNKS_PER_BATCH * B_)   // 640

typedef float  f32x4  __attribute__((ext_vector_type(4)));
typedef __bf16 bf16x8 __attribute__((ext_vector_type(8)));
typedef __bf16 bf16x4 __attribute__((ext_vector_type(4)));
typedef __bf16 bf16x2 __attribute__((ext_vector_type(2)));

#define MFMA16(a, b, c) __builtin_amdgcn_mfma_f32_16x16x32_bf16((a), (b), (c), 0, 0, 0)

// global->LDS async copy, 16B per lane (dest = wave-uniform base + lane*16)
#define GLOAD_LDS16(gp, lp)                                                     \
    __builtin_amdgcn_global_load_lds(                                           \
        (const __attribute__((address_space(1))) void*)(gp),                    \
        (__attribute__((address_space(3))) void*)(lp), 16, 0, 0)

// cumulative chunk count before q-block qb: g=qb>>3 -> 4g(g+1) + (qb&7)(g+1)
__device__ __forceinline__ int chunk_cum64(int qb) {
    int g = qb >> 3;
    return 4 * g * (g + 1) + (qb & 7) * (g + 1);
}

// ---------------------------------------------------------------------------
// Kernel 0: prep = x cast (blocks 0..6143) + weight transpose (6144..6431).
// ---------------------------------------------------------------------------
__global__ __launch_bounds__(256) void prep_kernel(const float* __restrict__ x,
                                                   const float* __restrict__ Wq,
                                                   const float* __restrict__ Wk,
                                                   const float* __restrict__ Wv,
                                                   __bf16* __restrict__ xb,
                                                   __bf16* __restrict__ wt_all,
                                                   float qscale) {
    const int bid = blockIdx.x;
    if (bid < 6144) {
        size_t i = ((size_t)bid * 256 + threadIdx.x) * 8;
        f32x4 a = *(const f32x4*)(x + i);
        f32x4 b = *(const f32x4*)(x + i + 4);
        bf16x8 o;
        o[0] = (__bf16)a[0]; o[1] = (__bf16)a[1]; o[2] = (__bf16)a[2]; o[3] = (__bf16)a[3];
        o[4] = (__bf16)b[0]; o[5] = (__bf16)b[1]; o[6] = (__bf16)b[2]; o[7] = (__bf16)b[3];
        *(bf16x8*)(xb + i) = o;
    } else {
        int idx = (bid - 6144) * 256 + threadIdx.x;   // [0, 73728)
        int n   = idx & 255;
        int t   = idx >> 8;          // [0, 288) = mat*96 + k8
        int mat = t / 96;
        int k8  = t - mat * 96;
        const float* W = (mat == 0) ? Wq : ((mat == 1) ? Wk : Wv);
        float scale = (mat == 0) ? qscale : 1.0f;
        bf16x8 o;
#pragma unroll
        for (int j = 0; j < 8; j++)
            o[j] = (__bf16)(W[(k8 * 8 + j) * HS_ + n] * scale);
        *(bf16x8*)&wt_all[((size_t)mat * HS_ + n) * C_ + k8 * 8] = o;
    }
}

// ---------------------------------------------------------------------------
// Kernel 2: fused QKV GEMM. BK=32, double-buffered LDS, one barrier/iter.
// R19 delta (ONLY change vs round-0 champion): LDS bank-conflict swizzle.
//   R18 PMC: SQ_LDS_BANK_CONFLICT = 2.36M here (8.7x flash_part) -- the
//   b128 fragment reads at 64 B row stride give 16 lanes only TWO start
//   banks (16*(R&1) + 4*quad) -> 8-way conflict. Fix per T2 + rule #21
//   (both-sides-or-neither with global_load_lds): LDS dest stays LINEAR,
//   the GLOBAL source is pre-swizzled -- 16B slot (row, sl) holds global
//   granule sl ^ ((row>>1)&3) -- and reads use slot quad ^ ((cm>>1)&3).
//   Start banks become all 8 of {0,4,..,28}, 2 lanes each = 2-way = free.
//   Global coalescing unchanged (permutation within each 64 B row).
// Fragment layouts (element index, all *8 = 8 bf16 per lane slot):
//   Q: ((((b*32+qt)*4 + w16)*8 + ks )*64 + lane)   lane&15 = q, quad = (d>>3)&3, j = d&7
//   K: ((((b*32+kt)*8 + ks )*4 + ns )*64 + lane)   lane&15 = s, quad = (d>>3)&3, j = d&7
//   V: ((((b*32+kt)*2 + ks2)*16 + ntv)*64 + lane)  lane&15 = d, quad = (s>>3)&3, j = s&7
// ---------------------------------------------------------------------------
__global__ __launch_bounds__(256) void proj_kernel(const __bf16* __restrict__ xb,
                                                   const __bf16* __restrict__ wt,
                                                   __bf16* __restrict__ qf_,
                                                   __bf16* __restrict__ kf_,
                                                   __bf16* __restrict__ vf_) {
    __shared__ alignas(16) __bf16 ldsA[2][128 * 32];   // 2 x 8 KB
    __shared__ alignas(16) __bf16 ldsB[2][128 * 32];   // 2 x 8 KB

    const int tid  = threadIdx.x;
    const int w    = tid >> 6;
    const int lane = tid & 63;
    const int cm   = lane & 15;
    const int quad = lane >> 4;
    const int wm   = w & 1;
    const int wn   = w >> 1;
    const int m0   = blockIdx.x * 128;
    const int n0   = blockIdx.y * 128;
    const int mat  = n0 >> 8;                 // 0=Q 1=K 2=V

    // swizzled 16B-slot for fragment reads: row R has global granule `quad`
    // stored at slot quad ^ ((R>>1)&3); R = (16-mult) + cm -> (R>>1)&3 = (cm>>1)&3
    const int sw = (quad ^ ((cm >> 1) & 3)) * 8;

    f32x4 acc[4][4];
#pragma unroll
    for (int i = 0; i < 4; i++)
#pragma unroll
        for (int j = 0; j < 4; j++) acc[i][j] = (f32x4){0.f, 0.f, 0.f, 0.f};

    // prologue: stage k-iter 0 into buffer 0 (global granule pre-swizzled)
#pragma unroll
    for (int h = 0; h < 2; h++) {
        int c  = tid + h * 256;   // 512 chunks: row = c>>2, LDS slot = c&3
        int gg = (c & 3) ^ ((c >> 3) & 3);   // global granule for this slot
        GLOAD_LDS16(xb + (size_t)(m0 + (c >> 2)) * C_ + gg * 8, &ldsA[0][c * 8]);
        GLOAD_LDS16(wt + (size_t)(n0 + (c >> 2)) * C_ + gg * 8, &ldsB[0][c * 8]);
    }

    for (int kt = 0; kt < 24; kt++) {
        const int cur = kt & 1;
        __syncthreads();   // drains vmcnt -> buf[cur] staged; prev reads done

        if (kt < 23) {
            const int k0 = (kt + 1) * 32;
#pragma unroll
            for (int h = 0; h < 2; h++) {
                int c  = tid + h * 256;
                int gg = (c & 3) ^ ((c >> 3) & 3);
                GLOAD_LDS16(xb + (size_t)(m0 + (c >> 2)) * C_ + k0 + gg * 8,
                            &ldsA[cur ^ 1][c * 8]);
                GLOAD_LDS16(wt + (size_t)(n0 + (c >> 2)) * C_ + k0 + gg * 8,
                            &ldsB[cur ^ 1][c * 8]);
            }
        }

        bf16x8 af[4], bfr[4];
#pragma unroll
        for (int mt = 0; mt < 4; mt++)
            af[mt] = *(const bf16x8*)&ldsA[cur][(wm * 64 + mt * 16 + cm) * 32 + sw];
#pragma unroll
        for (int nt = 0; nt < 4; nt++)
            bfr[nt] = *(const bf16x8*)&ldsB[cur][(wn * 64 + nt * 16 + cm) * 32 + sw];
        if (mat < 2) {
#pragma unroll
            for (int dt = 0; dt < 4; dt++)
#pragma unroll
                for (int qt2 = 0; qt2 < 4; qt2++)
                    acc[dt][qt2] = MFMA16(bfr[dt], af[qt2], acc[dt][qt2]);
        } else {
#pragma unroll
            for (int mt = 0; mt < 4; mt++)
#pragma unroll
                for (int nt = 0; nt < 4; nt++)
                    acc[mt][nt] = MFMA16(af[mt], bfr[nt], acc[mt][nt]);
        }
    }

    const int dBase = (n0 & 255) + wn * 64;
    const int b     = m0 >> 11;
    if (mat < 2) {
        const int rt2 = ((m0 & 2047) >> 6) + wm;   // 64-row tile within batch
        __bf16* dst = (mat == 0) ? qf_ : kf_;
#pragma unroll
        for (int dt = 0; dt < 4; dt++)
#pragma unroll
            for (int qt2 = 0; qt2 < 4; qt2++) {
                int d0    = dBase + dt * 16 + quad * 4;   // d of reg i = d0 + i
                int ksq   = d0 >> 5;
                int quadp = (d0 >> 3) & 3;
                int j0    = d0 & 7;
                size_t addr;
                if (mat == 0)
                    addr = ((((size_t)(b * 32 + rt2) * 4 + qt2) * 8 + ksq) * 64
                            + quadp * 16 + cm) * 8 + j0;
                else
                    addr = ((((size_t)(b * 32 + rt2) * 8 + ksq) * 4 + qt2) * 64
                            + quadp * 16 + cm) * 8 + j0;
                bf16x4 v4;
                v4[0] = (__bf16)acc[dt][qt2][0]; v4[1] = (__bf16)acc[dt][qt2][1];
                v4[2] = (__bf16)acc[dt][qt2][2]; v4[3] = (__bf16)acc[dt][qt2][3];
                *(bf16x4*)(dst + addr) = v4;
            }
    } else {
        const int rt = ((m0 & 2047) + wm * 64) >> 6;
#pragma unroll
        for (int mt = 0; mt < 4; mt++) {
            int ks2   = (mt >> 1) & 1;
            int quadF = (mt & 1) * 2 + (quad >> 1);
            int jb    = (quad & 1) * 4;
#pragma unroll
            for (int nt = 0; nt < 4; nt++) {
                int ntv = (dBase >> 4) + nt;
                size_t idx = ((((size_t)(b * 32 + rt) * 2 + ks2) * 16 + ntv) * 64
                              + quadF * 16 + cm) * 8 + jb;
                bf16x4 v4;
                v4[0] = (__bf16)acc[mt][nt][0]; v4[1] = (__bf16)acc[mt][nt][1];
                v4[2] = (__bf16)acc[mt][nt][2]; v4[3] = (__bf16)acc[mt][nt][3];
                *(bf16x4*)(vf_ + idx) = v4;
            }
        }
    }
}

// ---------------------------------------------------------------------------
// Kernel 3a: split-K causal flash partial — EXACT round-0 champion body
//   (32-key tiles, 36 KB LDS -> 3 blocks/CU, 512-key chunks, 640 blocks).
//   Fixed-anchor softmax, per-lane (q = cm), no rescale; P private per wave.
//   Conflict-free LDS reads (lane*16B contiguous) — PMC confirmed 270K only.
// ---------------------------------------------------------------------------
__global__ __launch_bounds__(256, 3) void flash_part(const __bf16* __restrict__ qf_,
                                                     const __bf16* __restrict__ kf_,
                                                     const __bf16* __restrict__ vf_,
                                                     __bf16* __restrict__ Opart,
                                                     float* __restrict__ mpart,
                                                     float* __restrict__ lpart) {
    __shared__ alignas(16) __bf16 ldsK[8 * 2 * 64 * 8];   // [ks8][ns2][lane]x8 = 16 KB
    __shared__ alignas(16) __bf16 ldsV[16 * 64 * 8];      // [ntv16][lane]x8  = 16 KB
    __shared__ alignas(16) __bf16 ldsP[4][512];           // per-wave P (1 KB)

    const int tid  = threadIdx.x;
    const int w    = tid >> 6;       // 0..3
    const int lane = tid & 63;
    const int cm   = lane & 15;      // = q column
    const int quad = lane >> 4;

    const int pid  = blockIdx.x;                // [0, 640)
    const int b    = pid & 7;                   // batch -> XCD spread
    const int r    = (CHUNKS_PER_BATCH - 1) - (pid >> 3);   // heavy chunks first
    int qb = 0, ci = 0;
    {
        int rr = r;
        for (int j = 0; j < 32; j++) {
            int c = (j >> 3) + 1;
            if (rr < c) { qb = j; ci = rr; break; }
            rr -= c;
        }
    }
    const int lpid = b * CHUNKS_PER_BATCH + r;  // output slot
    const int kt_begin = ci * 16;                       // 32-key tiles
    const int kt_end   = min(kt_begin + 16, 2 * qb + 2);

    // Q fragments (B-operand: lane&15 = q, quad*8+j = d), coalesced loads.
    const __bf16* qp = qf_ + (((size_t)(b * 32 + qb) * 4 + w) * 8) * 512 + lane * 8;
    bf16x8 qf[8];
#pragma unroll
    for (int ks = 0; ks < 8; ks++) qf[ks] = *(const bf16x8*)(qp + ks * 512);

    f32x4 accO[16];   // accO[nt][i]: d = nt*16 + quad*4 + i, q = cm
#pragma unroll
    for (int i = 0; i < 16; i++) accO[i] = (f32x4){0.f, 0.f, 0.f, 0.f};
    float mi = 0.f, li = 0.f;        // mi fixed after first tile

    const int wrow  = qb * 64 + w * 16;
    const int qglob = wrow + cm;

    for (int kt = kt_begin; kt < kt_end; kt++) {
        __syncthreads();   // (A) prior tile's LDS fully consumed

        // ---- stage K (16 KB) + V (16 KB) tile, async ----
        {
            const int kt64 = kt >> 1, kh = kt & 1;
            const __bf16* kgb = kf_ + (((size_t)(b * 32 + kt64) * 8) * 4 + kh * 2) * 512;
#pragma unroll
            for (int h = 0; h < 4; h++) {
                int g = h * 256 + tid;           // 16B slot id, 0..1023
                int ks = g >> 7, sub = g & 127;  // sub = ns2*64 + lane'
                GLOAD_LDS16(kgb + (size_t)ks * 4 * 512 + sub * 8,
                            ldsK + (h * 256 + w * 64) * 8);
            }
            const __bf16* vgb = vf_ + ((size_t)(b * 64 + kt) * 16) * 512;
#pragma unroll
            for (int h = 0; h < 4; h++) {
                int g = h * 256 + tid;           // ntv = g>>6, lane' = g&63
                GLOAD_LDS16(vgb + (size_t)g * 8,
                            ldsV + (h * 256 + w * 64) * 8);
            }
        }
        __syncthreads();   // (B) vmcnt drained -> K/V visible

        // ---- St = K Q^T  (32 s x 16 q per wave) ----
        f32x4 s[2];
#pragma unroll
        for (int i = 0; i < 2; i++) s[i] = (f32x4){0.f, 0.f, 0.f, 0.f};
#pragma unroll
        for (int ns = 0; ns < 2; ns++)
#pragma unroll
            for (int ks = 0; ks < 8; ks++) {
                bf16x8 kfr = *(const bf16x8*)&ldsK[(ks * 2 + ns) * 512 + lane * 8];
                s[ns] = MFMA16(kfr, qf[ks], s[ns]);
            }
        // ---- causal mask ----
        if (kt * 32 + 31 > wrow) {
#pragma unroll
            for (int ns = 0; ns < 2; ns++)
#pragma unroll
                for (int i = 0; i < 4; i++)
                    if (kt * 32 + ns * 16 + quad * 4 + i > qglob)
                        s[ns][i] = -__builtin_inff();
        }
        // ---- fixed-anchor softmax: establish m once (first tile) ----
        if (kt == kt_begin) {
            float pm = -__builtin_inff();
#pragma unroll
            for (int ns = 0; ns < 2; ns++)
#pragma unroll
                for (int i = 0; i < 4; i++) pm = fmaxf(pm, s[ns][i]);
            pm = fmaxf(pm, __shfl_xor(pm, 16));
            pm = fmaxf(pm, __shfl_xor(pm, 32));
            mi = pm;
        }
        float p[2][4], rs = 0.f;
#pragma unroll
        for (int ns = 0; ns < 2; ns++)
#pragma unroll
            for (int i = 0; i < 4; i++) {
                p[ns][i] = exp2f(s[ns][i] - mi);
                rs += p[ns][i];
            }
        rs += __shfl_xor(rs, 16);
        rs += __shfl_xor(rs, 32);
        li += rs;

        // ---- P -> private per-wave LDS in PV B-operand layout ----
#pragma unroll
        for (int ns = 0; ns < 2; ns++)
#pragma unroll
            for (int i2 = 0; i2 < 2; i2++) {
                bf16x2 d2;
                d2[0] = (__bf16)p[ns][2 * i2];
                d2[1] = (__bf16)p[ns][2 * i2 + 1];
                int off = ((ns * 2 + (quad >> 1)) * 16 + cm) * 8
                          + (quad & 1) * 4 + i2 * 2;
                *(bf16x2*)&ldsP[w][off] = d2;
            }
        // ---- O += V^T-frag x P-frag ----
        bf16x8 pfrag = *(const bf16x8*)&ldsP[w][(quad * 16 + cm) * 8];
#pragma unroll
        for (int nt = 0; nt < 16; nt++) {
            bf16x8 vfr = *(const bf16x8*)&ldsV[(nt * 64 + lane) * 8];
            accO[nt] = MFMA16(vfr, pfrag, accO[nt]);
        }
    }

    // ---- epilogue: coalesced bf16x4 stores + fp32 (m, l) ----
    __bf16* op = Opart + ((size_t)lpid * 64 + w * 16 + cm) * HS_;
#pragma unroll
    for (int nt = 0; nt < 16; nt++) {
        bf16x4 v4;
        v4[0] = (__bf16)accO[nt][0]; v4[1] = (__bf16)accO[nt][1];
        v4[2] = (__bf16)accO[nt][2]; v4[3] = (__bf16)accO[nt][3];
        *(bf16x4*)(op + nt * 16 + quad * 4) = v4;
    }
    if (quad == 0) {
        mpart[lpid * 64 + w * 16 + cm] = mi;
        lpart[lpid * 64 + w * 16 + cm] = li;
    }
}

// ---------------------------------------------------------------------------
// Kernel 3b: combine partials.  Grid (256, 4): block = (b, qb) x 16 rows.
// ---------------------------------------------------------------------------
__global__ __launch_bounds__(256) void flash_combine(const __bf16* __restrict__ Opart,
                                                     const float* __restrict__ mpart,
                                                     const float* __restrict__ lpart,
                                                     float* __restrict__ out) {
    const int b    = blockIdx.x >> 5;
    const int qb   = blockIdx.x & 31;
    const int nc   = (qb >> 3) + 1;
    const int pid0 = b * CHUNKS_PER_BATCH + chunk_cum64(qb);

    const int tid  = threadIdx.x;
    const int col  = (tid & 63) * 4;
    const int r0   = blockIdx.y * 16 + (tid >> 6) * 4;

    f32x4 ms = (f32x4){-__builtin_inff(), -__builtin_inff(),
                       -__builtin_inff(), -__builtin_inff()};
    for (int c = 0; c < nc; c++) {
        f32x4 m4 = *(const f32x4*)(mpart + (pid0 + c) * 64 + r0);
#pragma unroll
        for (int i = 0; i < 4; i++) ms[i] = fmaxf(ms[i], m4[i]);
    }
    f32x4 acc[4];
#pragma unroll
    for (int i = 0; i < 4; i++) acc[i] = (f32x4){0.f, 0.f, 0.f, 0.f};
    f32x4 lt = (f32x4){0.f, 0.f, 0.f, 0.f};
    for (int c = 0; c < nc; c++) {
        f32x4 m4 = *(const f32x4*)(mpart + (pid0 + c) * 64 + r0);
        f32x4 l4 = *(const f32x4*)(lpart + (pid0 + c) * 64 + r0);
#pragma unroll
        for (int i = 0; i < 4; i++) {
            float sc = exp2f(m4[i] - ms[i]);
            lt[i] += l4[i] * sc;
            bf16x4 o = *(const bf16x4*)(Opart
                        + ((size_t)(pid0 + c) * 64 + r0 + i) * HS_ + col);
            acc[i][0] += (float)o[0] * sc; acc[i][1] += (float)o[1] * sc;
            acc[i][2] += (float)o[2] * sc; acc[i][3] += (float)o[3] * sc;
        }
    }
#pragma unroll
    for (int i = 0; i < 4; i++) {
        float inv = 1.0f / lt[i];
        f32x4 res = (f32x4){acc[i][0] * inv, acc[i][1] * inv,
                            acc[i][2] * inv, acc[i][3] * inv};
        *(f32x4*)(out + ((size_t)(b * T_ + qb * 64 + r0 + i)) * HS_ + col) = res;
    }
}

// ---------------------------------------------------------------------------
extern "C" void kernel_launch(void* const* d_in, const int* in_sizes, int n_in,
                              void* d_out, int out_size, void* d_ws, size_t ws_size,
                              hipStream_t stream) {
    const float* x  = (const float*)d_in[0];
    const float* Wq = (const float*)d_in[1];
    const float* Wk = (const float*)d_in[2];
    const float* Wv = (const float*)d_in[3];
    float* out = (float*)d_out;

    char* ws = (char*)d_ws;
    size_t off = 0;
    __bf16* wt_all = (__bf16*)(ws + off); off += 1179648;
    __bf16* qfrag  = (__bf16*)(ws + off); off += 8388608;
    __bf16* kfrag  = (__bf16*)(ws + off); off += 8388608;
    __bf16* vfrag  = (__bf16*)(ws + off); off += 8388608;
    __bf16* xb     = (__bf16*)(ws + off);              // union with Opart
    __bf16* Opart  = (__bf16*)(ws + off); off += (size_t)NSLOT * 64 * HS_ * 2;
    float*  mpart  = (float*)(ws + off);  off += (size_t)NSLOT * 64 * 4;
    float*  lpart  = (float*)(ws + off);

    float qscale = 1.4426950408889634f / sqrtf((float)C_);

    prep_kernel<<<dim3(6432), 256, 0, stream>>>(x, Wq, Wk, Wv, xb, wt_all, qscale);
    proj_kernel<<<dim3(128, 6), 256, 0, stream>>>(xb, wt_all, qfrag, kfrag, vfrag);
    flash_part<<<dim3(NSLOT), 256, 0, stream>>>(qfrag, kfrag, vfrag, Opart, mpart, lpart);
    flash_combine<<<dim3(256, 4), 256, 0, stream>>>(Opart, mpart, lpart, out);
}

// Round 13
// 173.026 us; speedup vs baseline: 1.0827x; 1.0089x over previous
//
#include <hip/hip_runtime.h>
#include <hip/hip_bf16.h>
#include <math.h>

// Problem constants
#define B_  8
#define T_  2048
#define C_  768
#define HS_ 256

// Split-K flash: q-block = 64 rows, k-tile = 32 keys, chunk = 16 k-tiles
// (512 keys). q-block qb (0..31) has 2qb+2 k-tiles; chunks(qb) = (qb>>3)+1;
// per-batch chunk total = 80; blocks = 8 * 80 = 640.   (= round-0 champion)
#define CHUNKS_PER_BATCH 80
#define NSLOT (CHUNKS_PER_BATCH * B_)   // 640

typedef float  f32x4  __attribute__((ext_vector_type(4)));
typedef __bf16 bf16x8 __attribute__((ext_vector_type(8)));
typedef __bf16 bf16x4 __attribute__((ext_vector_type(4)));
typedef __bf16 bf16x2 __attribute__((ext_vector_type(2)));

#define MFMA16(a, b, c) __builtin_amdgcn_mfma_f32_16x16x32_bf16((a), (b), (c), 0, 0, 0)

// global->LDS async copy, 16B per lane (dest = wave-uniform base + lane*16)
#define GLOAD_LDS16(gp, lp)                                                     \
    __builtin_amdgcn_global_load_lds(                                           \
        (const __attribute__((address_space(1))) void*)(gp),                    \
        (__attribute__((address_space(3))) void*)(lp), 16, 0, 0)

// cumulative chunk count before q-block qb: g=qb>>3 -> 4g(g+1) + (qb&7)(g+1)
__device__ __forceinline__ int chunk_cum64(int qb) {
    int g = qb >> 3;
    return 4 * g * (g + 1) + (qb & 7) * (g + 1);
}

// ---------------------------------------------------------------------------
// Kernel 0: prep = x cast (blocks 0..6143) + weight transpose (6144..6431).
// ---------------------------------------------------------------------------
__global__ __launch_bounds__(256) void prep_kernel(const float* __restrict__ x,
                                                   const float* __restrict__ Wq,
                                                   const float* __restrict__ Wk,
                                                   const float* __restrict__ Wv,
                                                   __bf16* __restrict__ xb,
                                                   __bf16* __restrict__ wt_all,
                                                   float qscale) {
    const int bid = blockIdx.x;
    if (bid < 6144) {
        size_t i = ((size_t)bid * 256 + threadIdx.x) * 8;
        f32x4 a = *(const f32x4*)(x + i);
        f32x4 b = *(const f32x4*)(x + i + 4);
        bf16x8 o;
        o[0] = (__bf16)a[0]; o[1] = (__bf16)a[1]; o[2] = (__bf16)a[2]; o[3] = (__bf16)a[3];
        o[4] = (__bf16)b[0]; o[5] = (__bf16)b[1]; o[6] = (__bf16)b[2]; o[7] = (__bf16)b[3];
        *(bf16x8*)(xb + i) = o;
    } else {
        int idx = (bid - 6144) * 256 + threadIdx.x;   // [0, 73728)
        int n   = idx & 255;
        int t   = idx >> 8;          // [0, 288) = mat*96 + k8
        int mat = t / 96;
        int k8  = t - mat * 96;
        const float* W = (mat == 0) ? Wq : ((mat == 1) ? Wk : Wv);
        float scale = (mat == 0) ? qscale : 1.0f;
        bf16x8 o;
#pragma unroll
        for (int j = 0; j < 8; j++)
            o[j] = (__bf16)(W[(k8 * 8 + j) * HS_ + n] * scale);
        *(bf16x8*)&wt_all[((size_t)mat * HS_ + n) * C_ + k8 * 8] = o;
    }
}

// ---------------------------------------------------------------------------
// Kernel 2: fused QKV GEMM. BK=32, double-buffered LDS, one barrier/iter.
//   + R19 bank-conflict swizzle (pre-swizzled global source, linear LDS
//   dest, matching slot on fragment reads) — kept, neutral-at-worst.
// Fragment layouts (element index, all *8 = 8 bf16 per lane slot):
//   Q: ((((b*32+qt)*4 + w16)*8 + ks )*64 + lane)   lane&15 = q, quad = (d>>3)&3, j = d&7
//   K: ((((b*32+kt)*8 + ks )*4 + ns )*64 + lane)   lane&15 = s, quad = (d>>3)&3, j = d&7
//   V: ((((b*32+kt)*2 + ks2)*16 + ntv)*64 + lane)  lane&15 = d, quad = (s>>3)&3, j = s&7
// ---------------------------------------------------------------------------
__global__ __launch_bounds__(256) void proj_kernel(const __bf16* __restrict__ xb,
                                                   const __bf16* __restrict__ wt,
                                                   __bf16* __restrict__ qf_,
                                                   __bf16* __restrict__ kf_,
                                                   __bf16* __restrict__ vf_) {
    __shared__ alignas(16) __bf16 ldsA[2][128 * 32];   // 2 x 8 KB
    __shared__ alignas(16) __bf16 ldsB[2][128 * 32];   // 2 x 8 KB

    const int tid  = threadIdx.x;
    const int w    = tid >> 6;
    const int lane = tid & 63;
    const int cm   = lane & 15;
    const int quad = lane >> 4;
    const int wm   = w & 1;
    const int wn   = w >> 1;
    const int m0   = blockIdx.x * 128;
    const int n0   = blockIdx.y * 128;
    const int mat  = n0 >> 8;                 // 0=Q 1=K 2=V

    // swizzled 16B-slot for fragment reads: row R has global granule `quad`
    // stored at slot quad ^ ((R>>1)&3); R = (16-mult) + cm -> (R>>1)&3 = (cm>>1)&3
    const int sw = (quad ^ ((cm >> 1) & 3)) * 8;

    f32x4 acc[4][4];
#pragma unroll
    for (int i = 0; i < 4; i++)
#pragma unroll
        for (int j = 0; j < 4; j++) acc[i][j] = (f32x4){0.f, 0.f, 0.f, 0.f};

    // prologue: stage k-iter 0 into buffer 0 (global granule pre-swizzled)
#pragma unroll
    for (int h = 0; h < 2; h++) {
        int c  = tid + h * 256;   // 512 chunks: row = c>>2, LDS slot = c&3
        int gg = (c & 3) ^ ((c >> 3) & 3);   // global granule for this slot
        GLOAD_LDS16(xb + (size_t)(m0 + (c >> 2)) * C_ + gg * 8, &ldsA[0][c * 8]);
        GLOAD_LDS16(wt + (size_t)(n0 + (c >> 2)) * C_ + gg * 8, &ldsB[0][c * 8]);
    }

    for (int kt = 0; kt < 24; kt++) {
        const int cur = kt & 1;
        __syncthreads();   // drains vmcnt -> buf[cur] staged; prev reads done

        if (kt < 23) {
            const int k0 = (kt + 1) * 32;
#pragma unroll
            for (int h = 0; h < 2; h++) {
                int c  = tid + h * 256;
                int gg = (c & 3) ^ ((c >> 3) & 3);
                GLOAD_LDS16(xb + (size_t)(m0 + (c >> 2)) * C_ + k0 + gg * 8,
                            &ldsA[cur ^ 1][c * 8]);
                GLOAD_LDS16(wt + (size_t)(n0 + (c >> 2)) * C_ + k0 + gg * 8,
                            &ldsB[cur ^ 1][c * 8]);
            }
        }

        bf16x8 af[4], bfr[4];
#pragma unroll
        for (int mt = 0; mt < 4; mt++)
            af[mt] = *(const bf16x8*)&ldsA[cur][(wm * 64 + mt * 16 + cm) * 32 + sw];
#pragma unroll
        for (int nt = 0; nt < 4; nt++)
            bfr[nt] = *(const bf16x8*)&ldsB[cur][(wn * 64 + nt * 16 + cm) * 32 + sw];
        if (mat < 2) {
#pragma unroll
            for (int dt = 0; dt < 4; dt++)
#pragma unroll
                for (int qt2 = 0; qt2 < 4; qt2++)
                    acc[dt][qt2] = MFMA16(bfr[dt], af[qt2], acc[dt][qt2]);
        } else {
#pragma unroll
            for (int mt = 0; mt < 4; mt++)
#pragma unroll
                for (int nt = 0; nt < 4; nt++)
                    acc[mt][nt] = MFMA16(af[mt], bfr[nt], acc[mt][nt]);
        }
    }

    const int dBase = (n0 & 255) + wn * 64;
    const int b     = m0 >> 11;
    if (mat < 2) {
        const int rt2 = ((m0 & 2047) >> 6) + wm;   // 64-row tile within batch
        __bf16* dst = (mat == 0) ? qf_ : kf_;
#pragma unroll
        for (int dt = 0; dt < 4; dt++)
#pragma unroll
            for (int qt2 = 0; qt2 < 4; qt2++) {
                int d0    = dBase + dt * 16 + quad * 4;   // d of reg i = d0 + i
                int ksq   = d0 >> 5;
                int quadp = (d0 >> 3) & 3;
                int j0    = d0 & 7;
                size_t addr;
                if (mat == 0)
                    addr = ((((size_t)(b * 32 + rt2) * 4 + qt2) * 8 + ksq) * 64
                            + quadp * 16 + cm) * 8 + j0;
                else
                    addr = ((((size_t)(b * 32 + rt2) * 8 + ksq) * 4 + qt2) * 64
                            + quadp * 16 + cm) * 8 + j0;
                bf16x4 v4;
                v4[0] = (__bf16)acc[dt][qt2][0]; v4[1] = (__bf16)acc[dt][qt2][1];
                v4[2] = (__bf16)acc[dt][qt2][2]; v4[3] = (__bf16)acc[dt][qt2][3];
                *(bf16x4*)(dst + addr) = v4;
            }
    } else {
        const int rt = ((m0 & 2047) + wm * 64) >> 6;
#pragma unroll
        for (int mt = 0; mt < 4; mt++) {
            int ks2   = (mt >> 1) & 1;
            int quadF = (mt & 1) * 2 + (quad >> 1);
            int jb    = (quad & 1) * 4;
#pragma unroll
            for (int nt = 0; nt < 4; nt++) {
                int ntv = (dBase >> 4) + nt;
                size_t idx = ((((size_t)(b * 32 + rt) * 2 + ks2) * 16 + ntv) * 64
                              + quadF * 16 + cm) * 8 + jb;
                bf16x4 v4;
                v4[0] = (__bf16)acc[mt][nt][0]; v4[1] = (__bf16)acc[mt][nt][1];
                v4[2] = (__bf16)acc[mt][nt][2]; v4[3] = (__bf16)acc[mt][nt][3];
                *(bf16x4*)(vf_ + idx) = v4;
            }
        }
    }
}

// ---------------------------------------------------------------------------
// Kernel 3a: split-K causal flash partial — R20: champion body with PV
//   repartitioned by d. Old PV: every wave read the ENTIRE 16 KB V tile
//   (16 V-frags each; output partitioned by q) -> 68 of the block-tile's
//   132 b128 LDS reads. New PV: wave w owns d in [64w, 64w+64) for ALL 64
//   q rows -> 4 V-frags + 4 shared P-frags per wave (32 reads/block, -21%
//   on the binding LDS pipe; R17 accounting: pipe floor ~26us at 62% util
//   = measured 42us). P is now block-shared: one extra __syncthreads
//   between P-write and PV — pure sync, vmcnt already 0 (no VMEM issued
//   since barrier B). QK, softmax, staging, chunking, m/l all unchanged.
// ---------------------------------------------------------------------------
__global__ __launch_bounds__(256, 3) void flash_part(const __bf16* __restrict__ qf_,
                                                     const __bf16* __restrict__ kf_,
                                                     const __bf16* __restrict__ vf_,
                                                     __bf16* __restrict__ Opart,
                                                     float* __restrict__ mpart,
                                                     float* __restrict__ lpart) {
    __shared__ alignas(16) __bf16 ldsK[8 * 2 * 64 * 8];   // [ks8][ns2][lane]x8 = 16 KB
    __shared__ alignas(16) __bf16 ldsV[16 * 64 * 8];      // [ntv16][lane]x8  = 16 KB
    __shared__ alignas(16) __bf16 ldsP[4][512];           // per-q-tile P (shared, 4 KB)

    const int tid  = threadIdx.x;
    const int w    = tid >> 6;       // 0..3
    const int lane = tid & 63;
    const int cm   = lane & 15;      // = q column
    const int quad = lane >> 4;

    const int pid  = blockIdx.x;                // [0, 640)
    const int b    = pid & 7;                   // batch -> XCD spread
    const int r    = (CHUNKS_PER_BATCH - 1) - (pid >> 3);   // heavy chunks first
    int qb = 0, ci = 0;
    {
        int rr = r;
        for (int j = 0; j < 32; j++) {
            int c = (j >> 3) + 1;
            if (rr < c) { qb = j; ci = rr; break; }
            rr -= c;
        }
    }
    const int lpid = b * CHUNKS_PER_BATCH + r;  // output slot
    const int kt_begin = ci * 16;                       // 32-key tiles
    const int kt_end   = min(kt_begin + 16, 2 * qb + 2);

    // Q fragments (B-operand: lane&15 = q, quad*8+j = d), coalesced loads.
    const __bf16* qp = qf_ + (((size_t)(b * 32 + qb) * 4 + w) * 8) * 512 + lane * 8;
    bf16x8 qf[8];
#pragma unroll
    for (int ks = 0; ks < 8; ks++) qf[ks] = *(const bf16x8*)(qp + ks * 512);

    // accO[nt4][qt][i]: d = (w*4+nt4)*16 + quad*4 + i, q = qt*16 + cm
    f32x4 accO[4][4];
#pragma unroll
    for (int nt4 = 0; nt4 < 4; nt4++)
#pragma unroll
        for (int qt = 0; qt < 4; qt++) accO[nt4][qt] = (f32x4){0.f, 0.f, 0.f, 0.f};
    float mi = 0.f, li = 0.f;        // mi fixed after first tile (wave's q-tile = w)

    const int wrow  = qb * 64 + w * 16;
    const int qglob = wrow + cm;

    for (int kt = kt_begin; kt < kt_end; kt++) {
        __syncthreads();   // (A) prior tile's LDS (K/V/P) fully consumed

        // ---- stage K (16 KB) + V (16 KB) tile, async ----
        {
            const int kt64 = kt >> 1, kh = kt & 1;
            const __bf16* kgb = kf_ + (((size_t)(b * 32 + kt64) * 8) * 4 + kh * 2) * 512;
#pragma unroll
            for (int h = 0; h < 4; h++) {
                int g = h * 256 + tid;           // 16B slot id, 0..1023
                int ks = g >> 7, sub = g & 127;  // sub = ns2*64 + lane'
                GLOAD_LDS16(kgb + (size_t)ks * 4 * 512 + sub * 8,
                            ldsK + (h * 256 + w * 64) * 8);
            }
            const __bf16* vgb = vf_ + ((size_t)(b * 64 + kt) * 16) * 512;
#pragma unroll
            for (int h = 0; h < 4; h++) {
                int g = h * 256 + tid;           // ntv = g>>6, lane' = g&63
                GLOAD_LDS16(vgb + (size_t)g * 8,
                            ldsV + (h * 256 + w * 64) * 8);
            }
        }
        __syncthreads();   // (B) vmcnt drained -> K/V visible

        // ---- St = K Q^T  (32 s x 16 q per wave; wave's own q-tile w) ----
        f32x4 s[2];
#pragma unroll
        for (int i = 0; i < 2; i++) s[i] = (f32x4){0.f, 0.f, 0.f, 0.f};
#pragma unroll
        for (int ns = 0; ns < 2; ns++)
#pragma unroll
            for (int ks = 0; ks < 8; ks++) {
                bf16x8 kfr = *(const bf16x8*)&ldsK[(ks * 2 + ns) * 512 + lane * 8];
                s[ns] = MFMA16(kfr, qf[ks], s[ns]);
            }
        // ---- causal mask ----
        if (kt * 32 + 31 > wrow) {
#pragma unroll
            for (int ns = 0; ns < 2; ns++)
#pragma unroll
                for (int i = 0; i < 4; i++)
                    if (kt * 32 + ns * 16 + quad * 4 + i > qglob)
                        s[ns][i] = -__builtin_inff();
        }
        // ---- fixed-anchor softmax: establish m once (first tile) ----
        if (kt == kt_begin) {
            float pm = -__builtin_inff();
#pragma unroll
            for (int ns = 0; ns < 2; ns++)
#pragma unroll
                for (int i = 0; i < 4; i++) pm = fmaxf(pm, s[ns][i]);
            pm = fmaxf(pm, __shfl_xor(pm, 16));
            pm = fmaxf(pm, __shfl_xor(pm, 32));
            mi = pm;
        }
        float p[2][4], rs = 0.f;
#pragma unroll
        for (int ns = 0; ns < 2; ns++)
#pragma unroll
            for (int i = 0; i < 4; i++) {
                p[ns][i] = exp2f(s[ns][i] - mi);
                rs += p[ns][i];
            }
        rs += __shfl_xor(rs, 16);
        rs += __shfl_xor(rs, 32);
        li += rs;

        // ---- P (wave's q-tile w) -> shared LDS in PV B-operand layout ----
#pragma unroll
        for (int ns = 0; ns < 2; ns++)
#pragma unroll
            for (int i2 = 0; i2 < 2; i2++) {
                bf16x2 d2;
                d2[0] = (__bf16)p[ns][2 * i2];
                d2[1] = (__bf16)p[ns][2 * i2 + 1];
                int off = ((ns * 2 + (quad >> 1)) * 16 + cm) * 8
                          + (quad & 1) * 4 + i2 * 2;
                *(bf16x2*)&ldsP[w][off] = d2;
            }
        __syncthreads();   // (C) all 4 P tiles visible; vmcnt already 0 -> pure sync

        // ---- O += V^T-frag x P-frag; wave w owns d-slice [64w, 64w+64) ----
        bf16x8 pf[4];
#pragma unroll
        for (int qt = 0; qt < 4; qt++)
            pf[qt] = *(const bf16x8*)&ldsP[qt][(quad * 16 + cm) * 8];
#pragma unroll
        for (int nt4 = 0; nt4 < 4; nt4++) {
            bf16x8 vfr = *(const bf16x8*)&ldsV[((w * 4 + nt4) * 64 + lane) * 8];
#pragma unroll
            for (int qt = 0; qt < 4; qt++)
                accO[nt4][qt] = MFMA16(vfr, pf[qt], accO[nt4][qt]);
        }
    }

    // ---- epilogue: coalesced bf16x4 stores + fp32 (m, l) ----
#pragma unroll
    for (int qt = 0; qt < 4; qt++) {
        __bf16* op = Opart + ((size_t)lpid * 64 + qt * 16 + cm) * HS_;
#pragma unroll
        for (int nt4 = 0; nt4 < 4; nt4++) {
            bf16x4 v4;
            v4[0] = (__bf16)accO[nt4][qt][0]; v4[1] = (__bf16)accO[nt4][qt][1];
            v4[2] = (__bf16)accO[nt4][qt][2]; v4[3] = (__bf16)accO[nt4][qt][3];
            *(bf16x4*)(op + (w * 4 + nt4) * 16 + quad * 4) = v4;
        }
    }
    if (quad == 0) {
        mpart[lpid * 64 + w * 16 + cm] = mi;
        lpart[lpid * 64 + w * 16 + cm] = li;
    }
}

// ---------------------------------------------------------------------------
// Kernel 3b: combine partials.  Grid (256, 4): block = (b, qb) x 16 rows.
// ---------------------------------------------------------------------------
__global__ __launch_bounds__(256) void flash_combine(const __bf16* __restrict__ Opart,
                                                     const float* __restrict__ mpart,
                                                     const float* __restrict__ lpart,
                                                     float* __restrict__ out) {
    const int b    = blockIdx.x >> 5;
    const int qb   = blockIdx.x & 31;
    const int nc   = (qb >> 3) + 1;
    const int pid0 = b * CHUNKS_PER_BATCH + chunk_cum64(qb);

    const int tid  = threadIdx.x;
    const int col  = (tid & 63) * 4;
    const int r0   = blockIdx.y * 16 + (tid >> 6) * 4;

    f32x4 ms = (f32x4){-__builtin_inff(), -__builtin_inff(),
                       -__builtin_inff(), -__builtin_inff()};
    for (int c = 0; c < nc; c++) {
        f32x4 m4 = *(const f32x4*)(mpart + (pid0 + c) * 64 + r0);
#pragma unroll
        for (int i = 0; i < 4; i++) ms[i] = fmaxf(ms[i], m4[i]);
    }
    f32x4 acc[4];
#pragma unroll
    for (int i = 0; i < 4; i++) acc[i] = (f32x4){0.f, 0.f, 0.f, 0.f};
    f32x4 lt = (f32x4){0.f, 0.f, 0.f, 0.f};
    for (int c = 0; c < nc; c++) {
        f32x4 m4 = *(const f32x4*)(mpart + (pid0 + c) * 64 + r0);
        f32x4 l4 = *(const f32x4*)(lpart + (pid0 + c) * 64 + r0);
#pragma unroll
        for (int i = 0; i < 4; i++) {
            float sc = exp2f(m4[i] - ms[i]);
            lt[i] += l4[i] * sc;
            bf16x4 o = *(const bf16x4*)(Opart
                        + ((size_t)(pid0 + c) * 64 + r0 + i) * HS_ + col);
            acc[i][0] += (float)o[0] * sc; acc[i][1] += (float)o[1] * sc;
            acc[i][2] += (float)o[2] * sc; acc[i][3] += (float)o[3] * sc;
        }
    }
#pragma unroll
    for (int i = 0; i < 4; i++) {
        float inv = 1.0f / lt[i];
        f32x4 res = (f32x4){acc[i][0] * inv, acc[i][1] * inv,
                            acc[i][2] * inv, acc[i][3] * inv};
        *(f32x4*)(out + ((size_t)(b * T_ + qb * 64 + r0 + i)) * HS_ + col) = res;
    }
}

// ---------------------------------------------------------------------------
extern "C" void kernel_launch(void* const* d_in, const int* in_sizes, int n_in,
                              void* d_out, int out_size, void* d_ws, size_t ws_size,
                              hipStream_t stream) {
    const float* x  = (const float*)d_in[0];
    const float* Wq = (const float*)d_in[1];
    const float* Wk = (const float*)d_in[2];
    const float* Wv = (const float*)d_in[3];
    float* out = (float*)d_out;

    char* ws = (char*)d_ws;
    size_t off = 0;
    __bf16* wt_all = (__bf16*)(ws + off); off += 1179648;
    __bf16* qfrag  = (__bf16*)(ws + off); off += 8388608;
    __bf16* kfrag  = (__bf16*)(ws + off); off += 8388608;
    __bf16* vfrag  = (__bf16*)(ws + off); off += 8388608;
    __bf16* xb     = (__bf16*)(ws + off);              // union with Opart
    __bf16* Opart  = (__bf16*)(ws + off); off += (size_t)NSLOT * 64 * HS_ * 2;
    float*  mpart  = (float*)(ws + off);  off += (size_t)NSLOT * 64 * 4;
    float*  lpart  = (float*)(ws + off);

    float qscale = 1.4426950408889634f / sqrtf((float)C_);

    prep_kernel<<<dim3(6432), 256, 0, stream>>>(x, Wq, Wk, Wv, xb, wt_all, qscale);
    proj_kernel<<<dim3(128, 6), 256, 0, stream>>>(xb, wt_all, qfrag, kfrag, vfrag);
    flash_part<<<dim3(NSLOT), 256, 0, stream>>>(qfrag, kfrag, vfrag, Opart, mpart, lpart);
    flash_combine<<<dim3(256, 4), 256, 0, stream>>>(Opart, mpart, lpart, out);
}

// Round 14
// 171.388 us; speedup vs baseline: 1.0931x; 1.0096x over previous
//
#include <hip/hip_runtime.h>
#include <hip/hip_bf16.h>
#include <math.h>

// Problem constants
#define B_  8
#define T_  2048
#define C_  768
#define HS_ 256

// Split-K flash: q-block = 64 rows, k-tile = 32 keys, chunk = 16 k-tiles
// (512 keys). q-block qb (0..31) has 2qb+2 k-tiles; chunks(qb) = (qb>>3)+1;
// per-batch chunk total = 80; blocks = 8 * 80 = 640.
#define CHUNKS_PER_BATCH 80
#define NSLOT (CHUNKS_PER_BATCH * B_)   // 640

typedef float  f32x4  __attribute__((ext_vector_type(4)));
typedef __bf16 bf16x8 __attribute__((ext_vector_type(8)));
typedef __bf16 bf16x4 __attribute__((ext_vector_type(4)));
typedef __bf16 bf16x2 __attribute__((ext_vector_type(2)));

#define MFMA16(a, b, c) __builtin_amdgcn_mfma_f32_16x16x32_bf16((a), (b), (c), 0, 0, 0)

// global->LDS async copy, 16B per lane (dest = wave-uniform base + lane*16)
#define GLOAD_LDS16(gp, lp)                                                     \
    __builtin_amdgcn_global_load_lds(                                           \
        (const __attribute__((address_space(1))) void*)(gp),                    \
        (__attribute__((address_space(3))) void*)(lp), 16, 0, 0)

// cumulative chunk count before q-block qb: g=qb>>3 -> 4g(g+1) + (qb&7)(g+1)
__device__ __forceinline__ int chunk_cum64(int qb) {
    int g = qb >> 3;
    return 4 * g * (g + 1) + (qb & 7) * (g + 1);
}

// ---------------------------------------------------------------------------
// Kernel 0: prep = x cast (blocks 0..6143) + weight transpose (6144..6431).
// ---------------------------------------------------------------------------
__global__ __launch_bounds__(256) void prep_kernel(const float* __restrict__ x,
                                                   const float* __restrict__ Wq,
                                                   const float* __restrict__ Wk,
                                                   const float* __restrict__ Wv,
                                                   __bf16* __restrict__ xb,
                                                   __bf16* __restrict__ wt_all,
                                                   float qscale) {
    const int bid = blockIdx.x;
    if (bid < 6144) {
        size_t i = ((size_t)bid * 256 + threadIdx.x) * 8;
        f32x4 a = *(const f32x4*)(x + i);
        f32x4 b = *(const f32x4*)(x + i + 4);
        bf16x8 o;
        o[0] = (__bf16)a[0]; o[1] = (__bf16)a[1]; o[2] = (__bf16)a[2]; o[3] = (__bf16)a[3];
        o[4] = (__bf16)b[0]; o[5] = (__bf16)b[1]; o[6] = (__bf16)b[2]; o[7] = (__bf16)b[3];
        *(bf16x8*)(xb + i) = o;
    } else {
        int idx = (bid - 6144) * 256 + threadIdx.x;   // [0, 73728)
        int n   = idx & 255;
        int t   = idx >> 8;          // [0, 288) = mat*96 + k8
        int mat = t / 96;
        int k8  = t - mat * 96;
        const float* W = (mat == 0) ? Wq : ((mat == 1) ? Wk : Wv);
        float scale = (mat == 0) ? qscale : 1.0f;
        bf16x8 o;
#pragma unroll
        for (int j = 0; j < 8; j++)
            o[j] = (__bf16)(W[(k8 * 8 + j) * HS_ + n] * scale);
        *(bf16x8*)&wt_all[((size_t)mat * HS_ + n) * C_ + k8 * 8] = o;
    }
}

// ---------------------------------------------------------------------------
// Kernel 2: fused QKV GEMM. BK=32, double-buffered LDS, one barrier/iter.
//   + R19 bank-conflict swizzle (pre-swizzled global source, linear LDS
//   dest, matching slot on fragment reads).
// Fragment layouts (element index, all *8 = 8 bf16 per lane slot):
//   Q: ((((b*32+qt)*4 + w16)*8 + ks )*64 + lane)   lane&15 = q, quad = (d>>3)&3, j = d&7
//   K: ((((b*32+kt)*8 + ks )*4 + ns )*64 + lane)   lane&15 = s, quad = (d>>3)&3, j = d&7
//   V: ((((b*32+kt)*2 + ks2)*16 + ntv)*64 + lane)  lane&15 = d, quad = (s>>3)&3, j = s&7
// ---------------------------------------------------------------------------
__global__ __launch_bounds__(256) void proj_kernel(const __bf16* __restrict__ xb,
                                                   const __bf16* __restrict__ wt,
                                                   __bf16* __restrict__ qf_,
                                                   __bf16* __restrict__ kf_,
                                                   __bf16* __restrict__ vf_) {
    __shared__ alignas(16) __bf16 ldsA[2][128 * 32];   // 2 x 8 KB
    __shared__ alignas(16) __bf16 ldsB[2][128 * 32];   // 2 x 8 KB

    const int tid  = threadIdx.x;
    const int w    = tid >> 6;
    const int lane = tid & 63;
    const int cm   = lane & 15;
    const int quad = lane >> 4;
    const int wm   = w & 1;
    const int wn   = w >> 1;
    const int m0   = blockIdx.x * 128;
    const int n0   = blockIdx.y * 128;
    const int mat  = n0 >> 8;                 // 0=Q 1=K 2=V

    // swizzled 16B-slot for fragment reads: row R has global granule `quad`
    // stored at slot quad ^ ((R>>1)&3); R = (16-mult) + cm -> (R>>1)&3 = (cm>>1)&3
    const int sw = (quad ^ ((cm >> 1) & 3)) * 8;

    f32x4 acc[4][4];
#pragma unroll
    for (int i = 0; i < 4; i++)
#pragma unroll
        for (int j = 0; j < 4; j++) acc[i][j] = (f32x4){0.f, 0.f, 0.f, 0.f};

    // prologue: stage k-iter 0 into buffer 0 (global granule pre-swizzled)
#pragma unroll
    for (int h = 0; h < 2; h++) {
        int c  = tid + h * 256;   // 512 chunks: row = c>>2, LDS slot = c&3
        int gg = (c & 3) ^ ((c >> 3) & 3);   // global granule for this slot
        GLOAD_LDS16(xb + (size_t)(m0 + (c >> 2)) * C_ + gg * 8, &ldsA[0][c * 8]);
        GLOAD_LDS16(wt + (size_t)(n0 + (c >> 2)) * C_ + gg * 8, &ldsB[0][c * 8]);
    }

    for (int kt = 0; kt < 24; kt++) {
        const int cur = kt & 1;
        __syncthreads();   // drains vmcnt -> buf[cur] staged; prev reads done

        if (kt < 23) {
            const int k0 = (kt + 1) * 32;
#pragma unroll
            for (int h = 0; h < 2; h++) {
                int c  = tid + h * 256;
                int gg = (c & 3) ^ ((c >> 3) & 3);
                GLOAD_LDS16(xb + (size_t)(m0 + (c >> 2)) * C_ + k0 + gg * 8,
                            &ldsA[cur ^ 1][c * 8]);
                GLOAD_LDS16(wt + (size_t)(n0 + (c >> 2)) * C_ + k0 + gg * 8,
                            &ldsB[cur ^ 1][c * 8]);
            }
        }

        bf16x8 af[4], bfr[4];
#pragma unroll
        for (int mt = 0; mt < 4; mt++)
            af[mt] = *(const bf16x8*)&ldsA[cur][(wm * 64 + mt * 16 + cm) * 32 + sw];
#pragma unroll
        for (int nt = 0; nt < 4; nt++)
            bfr[nt] = *(const bf16x8*)&ldsB[cur][(wn * 64 + nt * 16 + cm) * 32 + sw];
        if (mat < 2) {
#pragma unroll
            for (int dt = 0; dt < 4; dt++)
#pragma unroll
                for (int qt2 = 0; qt2 < 4; qt2++)
                    acc[dt][qt2] = MFMA16(bfr[dt], af[qt2], acc[dt][qt2]);
        } else {
#pragma unroll
            for (int mt = 0; mt < 4; mt++)
#pragma unroll
                for (int nt = 0; nt < 4; nt++)
                    acc[mt][nt] = MFMA16(af[mt], bfr[nt], acc[mt][nt]);
        }
    }

    const int dBase = (n0 & 255) + wn * 64;
    const int b     = m0 >> 11;
    if (mat < 2) {
        const int rt2 = ((m0 & 2047) >> 6) + wm;   // 64-row tile within batch
        __bf16* dst = (mat == 0) ? qf_ : kf_;
#pragma unroll
        for (int dt = 0; dt < 4; dt++)
#pragma unroll
            for (int qt2 = 0; qt2 < 4; qt2++) {
                int d0    = dBase + dt * 16 + quad * 4;   // d of reg i = d0 + i
                int ksq   = d0 >> 5;
                int quadp = (d0 >> 3) & 3;
                int j0    = d0 & 7;
                size_t addr;
                if (mat == 0)
                    addr = ((((size_t)(b * 32 + rt2) * 4 + qt2) * 8 + ksq) * 64
                            + quadp * 16 + cm) * 8 + j0;
                else
                    addr = ((((size_t)(b * 32 + rt2) * 8 + ksq) * 4 + qt2) * 64
                            + quadp * 16 + cm) * 8 + j0;
                bf16x4 v4;
                v4[0] = (__bf16)acc[dt][qt2][0]; v4[1] = (__bf16)acc[dt][qt2][1];
                v4[2] = (__bf16)acc[dt][qt2][2]; v4[3] = (__bf16)acc[dt][qt2][3];
                *(bf16x4*)(dst + addr) = v4;
            }
    } else {
        const int rt = ((m0 & 2047) + wm * 64) >> 6;
#pragma unroll
        for (int mt = 0; mt < 4; mt++) {
            int ks2   = (mt >> 1) & 1;
            int quadF = (mt & 1) * 2 + (quad >> 1);
            int jb    = (quad & 1) * 4;
#pragma unroll
            for (int nt = 0; nt < 4; nt++) {
                int ntv = (dBase >> 4) + nt;
                size_t idx = ((((size_t)(b * 32 + rt) * 2 + ks2) * 16 + ntv) * 64
                              + quadF * 16 + cm) * 8 + jb;
                bf16x4 v4;
                v4[0] = (__bf16)acc[mt][nt][0]; v4[1] = (__bf16)acc[mt][nt][1];
                v4[2] = (__bf16)acc[mt][nt][2]; v4[3] = (__bf16)acc[mt][nt][3];
                *(bf16x4*)(vf_ + idx) = v4;
            }
        }
    }
}

// ---------------------------------------------------------------------------
// Kernel 3a: split-K causal flash partial — R21: R20 body (PV partitioned
//   by d, shared P) + SPLIT STAGING DRAIN. R20 post-mortem: -21% LDS reads
//   bought only -2% time -> LDS pipe is NOT the binder; the per-tile serial
//   path is, dominated by barrier B's full vmcnt(0) drain (all 32 KB K+V
//   must land before QK^T, ~700 cyc exposed). Fix (T4 counted-vmcnt,
//   semantics per m135: waits for outstanding-N OLDEST ops; K issued before
//   V): barrier B = s_waitcnt vmcnt(4) + raw s_barrier -> every wave's 4
//   K-loads done = K tile visible, V's 16 KB still in flight under
//   QK+softmax+P-write; barrier C = s_waitcnt vmcnt(0) + s_barrier (V
//   landed + P visible) right before PV. Barrier A stays __syncthreads
//   (full drain -> vmcnt=0 entering staging, so the counts are exact).
// ---------------------------------------------------------------------------
__global__ __launch_bounds__(256, 3) void flash_part(const __bf16* __restrict__ qf_,
                                                     const __bf16* __restrict__ kf_,
                                                     const __bf16* __restrict__ vf_,
                                                     __bf16* __restrict__ Opart,
                                                     float* __restrict__ mpart,
                                                     float* __restrict__ lpart) {
    __shared__ alignas(16) __bf16 ldsK[8 * 2 * 64 * 8];   // [ks8][ns2][lane]x8 = 16 KB
    __shared__ alignas(16) __bf16 ldsV[16 * 64 * 8];      // [ntv16][lane]x8  = 16 KB
    __shared__ alignas(16) __bf16 ldsP[4][512];           // per-q-tile P (shared, 4 KB)

    const int tid  = threadIdx.x;
    const int w    = tid >> 6;       // 0..3
    const int lane = tid & 63;
    const int cm   = lane & 15;      // = q column
    const int quad = lane >> 4;

    const int pid  = blockIdx.x;                // [0, 640)
    const int b    = pid & 7;                   // batch -> XCD spread
    const int r    = (CHUNKS_PER_BATCH - 1) - (pid >> 3);   // heavy chunks first
    int qb = 0, ci = 0;
    {
        int rr = r;
        for (int j = 0; j < 32; j++) {
            int c = (j >> 3) + 1;
            if (rr < c) { qb = j; ci = rr; break; }
            rr -= c;
        }
    }
    const int lpid = b * CHUNKS_PER_BATCH + r;  // output slot
    const int kt_begin = ci * 16;                       // 32-key tiles
    const int kt_end   = min(kt_begin + 16, 2 * qb + 2);

    // Q fragments (B-operand: lane&15 = q, quad*8+j = d), coalesced loads.
    const __bf16* qp = qf_ + (((size_t)(b * 32 + qb) * 4 + w) * 8) * 512 + lane * 8;
    bf16x8 qf[8];
#pragma unroll
    for (int ks = 0; ks < 8; ks++) qf[ks] = *(const bf16x8*)(qp + ks * 512);

    // accO[nt4][qt][i]: d = (w*4+nt4)*16 + quad*4 + i, q = qt*16 + cm
    f32x4 accO[4][4];
#pragma unroll
    for (int nt4 = 0; nt4 < 4; nt4++)
#pragma unroll
        for (int qt = 0; qt < 4; qt++) accO[nt4][qt] = (f32x4){0.f, 0.f, 0.f, 0.f};
    float mi = 0.f, li = 0.f;        // mi fixed after first tile (wave's q-tile = w)

    const int wrow  = qb * 64 + w * 16;
    const int qglob = wrow + cm;

    for (int kt = kt_begin; kt < kt_end; kt++) {
        __syncthreads();   // (A) prior tile's LDS consumed; full drain -> vmcnt=0

        // ---- stage K (16 KB) first, then V (16 KB); async ----
        {
            const int kt64 = kt >> 1, kh = kt & 1;
            const __bf16* kgb = kf_ + (((size_t)(b * 32 + kt64) * 8) * 4 + kh * 2) * 512;
#pragma unroll
            for (int h = 0; h < 4; h++) {
                int g = h * 256 + tid;           // 16B slot id, 0..1023
                int ks = g >> 7, sub = g & 127;  // sub = ns2*64 + lane'
                GLOAD_LDS16(kgb + (size_t)ks * 4 * 512 + sub * 8,
                            ldsK + (h * 256 + w * 64) * 8);
            }
            const __bf16* vgb = vf_ + ((size_t)(b * 64 + kt) * 16) * 512;
#pragma unroll
            for (int h = 0; h < 4; h++) {
                int g = h * 256 + tid;           // ntv = g>>6, lane' = g&63
                GLOAD_LDS16(vgb + (size_t)g * 8,
                            ldsV + (h * 256 + w * 64) * 8);
            }
        }
        // (B) K-only drain: wave's 4 oldest VMEM ops (= its K loads) done,
        //     then block barrier -> whole K tile visible. V stays in flight.
        asm volatile("s_waitcnt vmcnt(4)" ::: "memory");
        __builtin_amdgcn_s_barrier();

        // ---- St = K Q^T  (32 s x 16 q per wave; wave's own q-tile w) ----
        f32x4 s[2];
#pragma unroll
        for (int i = 0; i < 2; i++) s[i] = (f32x4){0.f, 0.f, 0.f, 0.f};
#pragma unroll
        for (int ns = 0; ns < 2; ns++)
#pragma unroll
            for (int ks = 0; ks < 8; ks++) {
                bf16x8 kfr = *(const bf16x8*)&ldsK[(ks * 2 + ns) * 512 + lane * 8];
                s[ns] = MFMA16(kfr, qf[ks], s[ns]);
            }
        // ---- causal mask ----
        if (kt * 32 + 31 > wrow) {
#pragma unroll
            for (int ns = 0; ns < 2; ns++)
#pragma unroll
                for (int i = 0; i < 4; i++)
                    if (kt * 32 + ns * 16 + quad * 4 + i > qglob)
                        s[ns][i] = -__builtin_inff();
        }
        // ---- fixed-anchor softmax: establish m once (first tile) ----
        if (kt == kt_begin) {
            float pm = -__builtin_inff();
#pragma unroll
            for (int ns = 0; ns < 2; ns++)
#pragma unroll
                for (int i = 0; i < 4; i++) pm = fmaxf(pm, s[ns][i]);
            pm = fmaxf(pm, __shfl_xor(pm, 16));
            pm = fmaxf(pm, __shfl_xor(pm, 32));
            mi = pm;
        }
        float p[2][4], rs = 0.f;
#pragma unroll
        for (int ns = 0; ns < 2; ns++)
#pragma unroll
            for (int i = 0; i < 4; i++) {
                p[ns][i] = exp2f(s[ns][i] - mi);
                rs += p[ns][i];
            }
        rs += __shfl_xor(rs, 16);
        rs += __shfl_xor(rs, 32);
        li += rs;

        // ---- P (wave's q-tile w) -> shared LDS in PV B-operand layout ----
#pragma unroll
        for (int ns = 0; ns < 2; ns++)
#pragma unroll
            for (int i2 = 0; i2 < 2; i2++) {
                bf16x2 d2;
                d2[0] = (__bf16)p[ns][2 * i2];
                d2[1] = (__bf16)p[ns][2 * i2 + 1];
                int off = ((ns * 2 + (quad >> 1)) * 16 + cm) * 8
                          + (quad & 1) * 4 + i2 * 2;
                *(bf16x2*)&ldsP[w][off] = d2;
            }
        // (C) V drain + P visibility: V landed for all waves, P tiles shared.
        asm volatile("s_waitcnt vmcnt(0)" ::: "memory");
        __builtin_amdgcn_s_barrier();

        // ---- O += V^T-frag x P-frag; wave w owns d-slice [64w, 64w+64) ----
        bf16x8 pf[4];
#pragma unroll
        for (int qt = 0; qt < 4; qt++)
            pf[qt] = *(const bf16x8*)&ldsP[qt][(quad * 16 + cm) * 8];
#pragma unroll
        for (int nt4 = 0; nt4 < 4; nt4++) {
            bf16x8 vfr = *(const bf16x8*)&ldsV[((w * 4 + nt4) * 64 + lane) * 8];
#pragma unroll
            for (int qt = 0; qt < 4; qt++)
                accO[nt4][qt] = MFMA16(vfr, pf[qt], accO[nt4][qt]);
        }
    }

    // ---- epilogue: coalesced bf16x4 stores + fp32 (m, l) ----
#pragma unroll
    for (int qt = 0; qt < 4; qt++) {
        __bf16* op = Opart + ((size_t)lpid * 64 + qt * 16 + cm) * HS_;
#pragma unroll
        for (int nt4 = 0; nt4 < 4; nt4++) {
            bf16x4 v4;
            v4[0] = (__bf16)accO[nt4][qt][0]; v4[1] = (__bf16)accO[nt4][qt][1];
            v4[2] = (__bf16)accO[nt4][qt][2]; v4[3] = (__bf16)accO[nt4][qt][3];
            *(bf16x4*)(op + (w * 4 + nt4) * 16 + quad * 4) = v4;
        }
    }
    if (quad == 0) {
        mpart[lpid * 64 + w * 16 + cm] = mi;
        lpart[lpid * 64 + w * 16 + cm] = li;
    }
}

// ---------------------------------------------------------------------------
// Kernel 3b: combine partials.  Grid (256, 4): block = (b, qb) x 16 rows.
// ---------------------------------------------------------------------------
__global__ __launch_bounds__(256) void flash_combine(const __bf16* __restrict__ Opart,
                                                     const float* __restrict__ mpart,
                                                     const float* __restrict__ lpart,
                                                     float* __restrict__ out) {
    const int b    = blockIdx.x >> 5;
    const int qb   = blockIdx.x & 31;
    const int nc   = (qb >> 3) + 1;
    const int pid0 = b * CHUNKS_PER_BATCH + chunk_cum64(qb);

    const int tid  = threadIdx.x;
    const int col  = (tid & 63) * 4;
    const int r0   = blockIdx.y * 16 + (tid >> 6) * 4;

    f32x4 ms = (f32x4){-__builtin_inff(), -__builtin_inff(),
                       -__builtin_inff(), -__builtin_inff()};
    for (int c = 0; c < nc; c++) {
        f32x4 m4 = *(const f32x4*)(mpart + (pid0 + c) * 64 + r0);
#pragma unroll
        for (int i = 0; i < 4; i++) ms[i] = fmaxf(ms[i], m4[i]);
    }
    f32x4 acc[4];
#pragma unroll
    for (int i = 0; i < 4; i++) acc[i] = (f32x4){0.f, 0.f, 0.f, 0.f};
    f32x4 lt = (f32x4){0.f, 0.f, 0.f, 0.f};
    for (int c = 0; c < nc; c++) {
        f32x4 m4 = *(const f32x4*)(mpart + (pid0 + c) * 64 + r0);
        f32x4 l4 = *(const f32x4*)(lpart + (pid0 + c) * 64 + r0);
#pragma unroll
        for (int i = 0; i < 4; i++) {
            float sc = exp2f(m4[i] - ms[i]);
            lt[i] += l4[i] * sc;
            bf16x4 o = *(const bf16x4*)(Opart
                        + ((size_t)(pid0 + c) * 64 + r0 + i) * HS_ + col);
            acc[i][0] += (float)o[0] * sc; acc[i][1] += (float)o[1] * sc;
            acc[i][2] += (float)o[2] * sc; acc[i][3] += (float)o[3] * sc;
        }
    }
#pragma unroll
    for (int i = 0; i < 4; i++) {
        float inv = 1.0f / lt[i];
        f32x4 res = (f32x4){acc[i][0] * inv, acc[i][1] * inv,
                            acc[i][2] * inv, acc[i][3] * inv};
        *(f32x4*)(out + ((size_t)(b * T_ + qb * 64 + r0 + i)) * HS_ + col) = res;
    }
}

// ---------------------------------------------------------------------------
extern "C" void kernel_launch(void* const* d_in, const int* in_sizes, int n_in,
                              void* d_out, int out_size, void* d_ws, size_t ws_size,
                              hipStream_t stream) {
    const float* x  = (const float*)d_in[0];
    const float* Wq = (const float*)d_in[1];
    const float* Wk = (const float*)d_in[2];
    const float* Wv = (const float*)d_in[3];
    float* out = (float*)d_out;

    char* ws = (char*)d_ws;
    size_t off = 0;
    __bf16* wt_all = (__bf16*)(ws + off); off += 1179648;
    __bf16* qfrag  = (__bf16*)(ws + off); off += 8388608;
    __bf16* kfrag  = (__bf16*)(ws + off); off += 8388608;
    __bf16* vfrag  = (__bf16*)(ws + off); off += 8388608;
    __bf16* xb     = (__bf16*)(ws + off);              // union with Opart
    __bf16* Opart  = (__bf16*)(ws + off); off += (size_t)NSLOT * 64 * HS_ * 2;
    float*  mpart  = (float*)(ws + off);  off += (size_t)NSLOT * 64 * 4;
    float*  lpart  = (float*)(ws + off);

    float qscale = 1.4426950408889634f / sqrtf((float)C_);

    prep_kernel<<<dim3(6432), 256, 0, stream>>>(x, Wq, Wk, Wv, xb, wt_all, qscale);
    proj_kernel<<<dim3(128, 6), 256, 0, stream>>>(xb, wt_all, qfrag, kfrag, vfrag);
    flash_part<<<dim3(NSLOT), 256, 0, stream>>>(qfrag, kfrag, vfrag, Opart, mpart, lpart);
    flash_combine<<<dim3(256, 4), 256, 0, stream>>>(Opart, mpart, lpart, out);
}